// Round 1
// baseline (323.016 us; speedup 1.0000x reference)
//
#include <hip/hip_runtime.h>

constexpr int NNODES_C = 50000;
constexpr int D = 16;
constexpr int NT = 16;

// d_ws layout (bytes):
//   dcnt : int[NNODES*NT]   @ 0            (3,200,000 B)  net type counts
//   deg  : int[NNODES]      @ 3,200,000    (200,000 B)    in-degree
//   tcnt : int[NT]          @ 3,400,000    (64 B)         per-type node count
//   tlist: int[NT*NNODES]   @ 3,400,064    (3,200,000 B)  per-type node lists
constexpr size_t OFF_DCNT  = 0;
constexpr size_t OFF_DEG   = 3200000;
constexpr size_t OFF_TCNT  = 3400000;
constexpr size_t OFF_TLIST = 3400064;
constexpr size_t ZERO_BYTES = OFF_TLIST; // zero dcnt+deg+tcnt each call

__global__ void edge_kernel(const int* __restrict__ ei,
                            const int* __restrict__ types,
                            int* __restrict__ dcnt,
                            int* __restrict__ deg,
                            int E) {
    int e = blockIdx.x * blockDim.x + threadIdx.x;
    if (e >= E) return;
    int s = ei[e];         // src row
    int t = ei[E + e];     // dst row
    int ts = types[s];
    int td = types[t];
    atomicAdd(&dcnt[s * NT + td],  1);  // +R[t_s, t_d] at src
    atomicAdd(&dcnt[t * NT + ts], -1);  // -R[t_d, t_s] at dst
    atomicAdd(&deg[t], 1);              // in-degree at dst
}

__global__ void list_kernel(const int* __restrict__ types,
                            int* __restrict__ tcnt,
                            int* __restrict__ tlist,
                            int N) {
    int n = blockIdx.x * blockDim.x + threadIdx.x;
    if (n >= N) return;
    int ty = types[n];
    int pos = atomicAdd(&tcnt[ty], 1);
    tlist[ty * NNODES_C + pos] = n;
}

__global__ __launch_bounds__(256)
void node_kernel(const float* __restrict__ reps,
                 const float* __restrict__ rmaps,
                 const int* __restrict__ dcnt,
                 const int* __restrict__ deg,
                 const int* __restrict__ tcnt,
                 const int* __restrict__ tlist,
                 float* __restrict__ out,
                 int N) {
    const int ty  = blockIdx.y;                  // block-uniform type
    const int cnt = tcnt[ty];
    if (blockIdx.x * 256 >= cnt) return;         // whole block empty

    float part = 0.0f;
    const int i = blockIdx.x * 256 + threadIdx.x;
    if (i < cnt) {
        const int n  = tlist[ty * NNODES_C + i];
        const int dg = deg[n];
        if (dg > 0) {
            float x[D];
            #pragma unroll
            for (int j = 0; j < D; ++j) x[j] = reps[j * N + n];

            int carr[NT];
            #pragma unroll
            for (int t = 0; t < NT; ++t) carr[t] = dcnt[n * NT + t];

            // wave-uniform R base: all lanes in the block share type ty
            const float* __restrict__ Rb = rmaps + (size_t)ty * NT * D * D;

            float y[D];
            #pragma unroll
            for (int r = 0; r < D; ++r) y[r] = 0.0f;

            #pragma unroll 1
            for (int t = 0; t < NT; ++t) {
                const float ct = (float)carr[t];
                const float* __restrict__ Rt = Rb + t * D * D;
                #pragma unroll
                for (int r = 0; r < D; ++r) {
                    float s = 0.0f;
                    #pragma unroll
                    for (int j = 0; j < D; ++j)
                        s = fmaf(Rt[r * D + j], x[j], s);
                    y[r] = fmaf(ct, s, y[r]);
                }
            }
            float ss = 0.0f;
            #pragma unroll
            for (int r = 0; r < D; ++r) ss = fmaf(y[r], y[r], ss);
            part = ss / (float)dg;
        }
    }

    // block reduction -> single atomic
    #pragma unroll
    for (int off = 32; off > 0; off >>= 1)
        part += __shfl_down(part, off);
    __shared__ float wpart[4];
    const int lane = threadIdx.x & 63;
    const int wid  = threadIdx.x >> 6;
    if (lane == 0) wpart[wid] = part;
    __syncthreads();
    if (threadIdx.x == 0)
        atomicAdd(out, wpart[0] + wpart[1] + wpart[2] + wpart[3]);
}

extern "C" void kernel_launch(void* const* d_in, const int* in_sizes, int n_in,
                              void* d_out, int out_size, void* d_ws, size_t ws_size,
                              hipStream_t stream) {
    const float* reps  = (const float*)d_in[0];   // [16, N]
    const float* rmaps = (const float*)d_in[1];   // [16,16,16,16]
    const int*   ei    = (const int*)d_in[2];     // [2, E]
    const int*   types = (const int*)d_in[3];     // [N]
    float* out = (float*)d_out;

    const int E = in_sizes[2] / 2;
    const int N = in_sizes[3];

    char* ws = (char*)d_ws;
    int* dcnt  = (int*)(ws + OFF_DCNT);
    int* deg   = (int*)(ws + OFF_DEG);
    int* tcnt  = (int*)(ws + OFF_TCNT);
    int* tlist = (int*)(ws + OFF_TLIST);

    hipMemsetAsync(d_ws, 0, ZERO_BYTES, stream);
    hipMemsetAsync(d_out, 0, sizeof(float), stream);

    edge_kernel<<<(E + 255) / 256, 256, 0, stream>>>(ei, types, dcnt, deg, E);
    list_kernel<<<(N + 255) / 256, 256, 0, stream>>>(types, tcnt, tlist, N);

    dim3 grid((N + 255) / 256, NT);
    node_kernel<<<grid, 256, 0, stream>>>(reps, rmaps, dcnt, deg, tcnt, tlist, out, N);
}

// Round 2
// 180.665 us; speedup vs baseline: 1.7879x; 1.7879x over previous
//
#include <hip/hip_runtime.h>

constexpr int NNODES_C = 50000;
constexpr int D = 16;
constexpr int NT = 16;

// d_ws layout (bytes):
//   dcnt : int[NNODES*NT]   @ 0            (3,200,000 B)  net type counts
//   deg  : int[NNODES]      @ 3,200,000    (200,000 B)    in-degree
//   tcnt : int[NT]          @ 3,400,000    (64 B)         per-type node count
//   tlist: int[NT*NNODES]   @ 3,400,064    (3,200,000 B)  per-type node lists
constexpr size_t OFF_DCNT  = 0;
constexpr size_t OFF_DEG   = 3200000;
constexpr size_t OFF_TCNT  = 3400000;
constexpr size_t OFF_TLIST = 3400064;
constexpr size_t ZERO_BYTES = OFF_TLIST; // zero dcnt+deg+tcnt each call

__global__ __launch_bounds__(256)
void edge_kernel(const int* __restrict__ ei,
                 const int* __restrict__ types,
                 int* __restrict__ dcnt,
                 int* __restrict__ deg,
                 int E) {
    const int i = (blockIdx.x * blockDim.x + threadIdx.x) * 4;
    if (i >= E) return;
    if (i + 3 < E) {
        const int4 s4 = *reinterpret_cast<const int4*>(ei + i);
        const int4 t4 = *reinterpret_cast<const int4*>(ei + E + i);
        const int ss[4] = {s4.x, s4.y, s4.z, s4.w};
        const int tt[4] = {t4.x, t4.y, t4.z, t4.w};
        #pragma unroll
        for (int k = 0; k < 4; ++k) {
            const int ts = types[ss[k]];
            const int td = types[tt[k]];
            atomicAdd(&dcnt[ss[k] * NT + td],  1);
            atomicAdd(&dcnt[tt[k] * NT + ts], -1);
            atomicAdd(&deg[tt[k]], 1);
        }
    } else {
        for (int e = i; e < E; ++e) {
            const int s = ei[e];
            const int t = ei[E + e];
            const int ts = types[s];
            const int td = types[t];
            atomicAdd(&dcnt[s * NT + td],  1);
            atomicAdd(&dcnt[t * NT + ts], -1);
            atomicAdd(&deg[t], 1);
        }
    }
}

__global__ __launch_bounds__(256)
void list_kernel(const int* __restrict__ types,
                 int* __restrict__ tcnt,
                 int* __restrict__ tlist,
                 int N) {
    __shared__ int lcnt[NT];
    __shared__ int lbase[NT];
    if (threadIdx.x < NT) lcnt[threadIdx.x] = 0;
    __syncthreads();

    const int n = blockIdx.x * 256 + threadIdx.x;
    int ty = 0, lr = 0;
    const bool valid = (n < N);
    if (valid) {
        ty = types[n];
        lr = atomicAdd(&lcnt[ty], 1);        // LDS atomic: cheap, <=16-way
    }
    __syncthreads();

    if (threadIdx.x < NT)
        lbase[threadIdx.x] = atomicAdd(&tcnt[threadIdx.x], lcnt[threadIdx.x]);
    __syncthreads();

    if (valid)
        tlist[ty * NNODES_C + lbase[ty] + lr] = n;
}

__global__ __launch_bounds__(256)
void node_kernel(const float* __restrict__ reps,
                 const float* __restrict__ rmaps,
                 const int* __restrict__ dcnt,
                 const int* __restrict__ deg,
                 const int* __restrict__ tcnt,
                 const int* __restrict__ tlist,
                 float* __restrict__ out,
                 int N) {
    const int ty  = blockIdx.y;                  // block-uniform type
    const int cnt = tcnt[ty];
    if (blockIdx.x * 256 >= cnt) return;         // whole block empty

    float part = 0.0f;
    const int i = blockIdx.x * 256 + threadIdx.x;
    if (i < cnt) {
        const int n  = tlist[ty * NNODES_C + i];
        const int dg = deg[n];
        if (dg > 0) {
            float x[D];
            #pragma unroll
            for (int j = 0; j < D; ++j) x[j] = reps[j * N + n];

            int carr[NT];
            #pragma unroll
            for (int t = 0; t < NT; ++t) carr[t] = dcnt[n * NT + t];

            // wave-uniform R base: all lanes in the block share type ty
            const float* __restrict__ Rb = rmaps + (size_t)ty * NT * D * D;

            float y[D];
            #pragma unroll
            for (int r = 0; r < D; ++r) y[r] = 0.0f;

            #pragma unroll 1
            for (int t = 0; t < NT; ++t) {
                const float ct = (float)carr[t];
                const float* __restrict__ Rt = Rb + t * D * D;
                #pragma unroll
                for (int r = 0; r < D; ++r) {
                    float s = 0.0f;
                    #pragma unroll
                    for (int j = 0; j < D; ++j)
                        s = fmaf(Rt[r * D + j], x[j], s);
                    y[r] = fmaf(ct, s, y[r]);
                }
            }
            float ss = 0.0f;
            #pragma unroll
            for (int r = 0; r < D; ++r) ss = fmaf(y[r], y[r], ss);
            part = ss / (float)dg;
        }
    }

    // block reduction -> single atomic
    #pragma unroll
    for (int off = 32; off > 0; off >>= 1)
        part += __shfl_down(part, off);
    __shared__ float wpart[4];
    const int lane = threadIdx.x & 63;
    const int wid  = threadIdx.x >> 6;
    if (lane == 0) wpart[wid] = part;
    __syncthreads();
    if (threadIdx.x == 0)
        atomicAdd(out, wpart[0] + wpart[1] + wpart[2] + wpart[3]);
}

extern "C" void kernel_launch(void* const* d_in, const int* in_sizes, int n_in,
                              void* d_out, int out_size, void* d_ws, size_t ws_size,
                              hipStream_t stream) {
    const float* reps  = (const float*)d_in[0];   // [16, N]
    const float* rmaps = (const float*)d_in[1];   // [16,16,16,16]
    const int*   ei    = (const int*)d_in[2];     // [2, E]
    const int*   types = (const int*)d_in[3];     // [N]
    float* out = (float*)d_out;

    const int E = in_sizes[2] / 2;
    const int N = in_sizes[3];

    char* ws = (char*)d_ws;
    int* dcnt  = (int*)(ws + OFF_DCNT);
    int* deg   = (int*)(ws + OFF_DEG);
    int* tcnt  = (int*)(ws + OFF_TCNT);
    int* tlist = (int*)(ws + OFF_TLIST);

    hipMemsetAsync(d_ws, 0, ZERO_BYTES, stream);
    hipMemsetAsync(d_out, 0, sizeof(float), stream);

    edge_kernel<<<(E / 4 + 255) / 256, 256, 0, stream>>>(ei, types, dcnt, deg, E);
    list_kernel<<<(N + 255) / 256, 256, 0, stream>>>(types, tcnt, tlist, N);

    dim3 grid((N + 255) / 256, NT);
    node_kernel<<<grid, 256, 0, stream>>>(reps, rmaps, dcnt, deg, tcnt, tlist, out, N);
}

// Round 3
// 123.254 us; speedup vs baseline: 2.6207x; 1.4658x over previous
//
#include <hip/hip_runtime.h>

constexpr int NNODES_C = 50000;
constexpr int D = 16;
constexpr int NT = 16;

// d_ws layout (bytes):
//   pk   : u32[NNODES*NT]  @ 0           (3,200,000 B)
//          low16 = #out-edges to type t, high16 = #in-edges from type t
//   tcnt : int[NT]         @ 3,200,000   (64 B)
//   tlist: int[NT*NNODES]  @ 3,200,064   (3,200,000 B)
constexpr size_t OFF_PK    = 0;
constexpr size_t OFF_TCNT  = 3200000;
constexpr size_t OFF_TLIST = 3200064;
constexpr size_t ZERO_BYTES = OFF_TLIST; // zero pk + tcnt each call

__global__ __launch_bounds__(256)
void edge_kernel(const int* __restrict__ ei,
                 const int* __restrict__ types,
                 unsigned int* __restrict__ pk,
                 int E) {
    const int i = (blockIdx.x * blockDim.x + threadIdx.x) * 4;
    if (i >= E) return;
    if (i + 3 < E) {
        const int4 s4 = *reinterpret_cast<const int4*>(ei + i);
        const int4 t4 = *reinterpret_cast<const int4*>(ei + E + i);
        const int ss[4] = {s4.x, s4.y, s4.z, s4.w};
        const int tt[4] = {t4.x, t4.y, t4.z, t4.w};
        #pragma unroll
        for (int k = 0; k < 4; ++k) {
            const int ts = types[ss[k]];
            const int td = types[tt[k]];
            atomicAdd(&pk[ss[k] * NT + td], 1u);        // out-count at src
            atomicAdd(&pk[tt[k] * NT + ts], 0x10000u);  // in-count at dst
        }
    } else {
        for (int e = i; e < E; ++e) {
            const int s = ei[e];
            const int t = ei[E + e];
            atomicAdd(&pk[s * NT + types[t]], 1u);
            atomicAdd(&pk[t * NT + types[s]], 0x10000u);
        }
    }
}

__global__ __launch_bounds__(256)
void list_kernel(const int* __restrict__ types,
                 int* __restrict__ tcnt,
                 int* __restrict__ tlist,
                 int N) {
    __shared__ int lcnt[NT];
    __shared__ int lbase[NT];
    if (threadIdx.x < NT) lcnt[threadIdx.x] = 0;
    __syncthreads();

    const int n = blockIdx.x * 256 + threadIdx.x;
    int ty = 0, lr = 0;
    const bool valid = (n < N);
    if (valid) {
        ty = types[n];
        lr = atomicAdd(&lcnt[ty], 1);        // LDS atomic: cheap
    }
    __syncthreads();

    if (threadIdx.x < NT)
        lbase[threadIdx.x] = atomicAdd(&tcnt[threadIdx.x], lcnt[threadIdx.x]);
    __syncthreads();

    if (valid)
        tlist[ty * NNODES_C + lbase[ty] + lr] = n;
}

__global__ __launch_bounds__(256)
void node_kernel(const float* __restrict__ reps,
                 const float* __restrict__ rmaps,
                 const unsigned int* __restrict__ pk,
                 const int* __restrict__ tcnt,
                 const int* __restrict__ tlist,
                 float* __restrict__ out,
                 int N) {
    const int ty  = blockIdx.y;                  // block-uniform type
    const int cnt = tcnt[ty];

    float part = 0.0f;
    for (int i = blockIdx.x * 256 + threadIdx.x; i < cnt;
         i += gridDim.x * 256) {
        const int n = tlist[ty * NNODES_C + i];

        const uint4* prow = reinterpret_cast<const uint4*>(pk + (size_t)n * NT);
        const uint4 w0 = prow[0], w1 = prow[1], w2 = prow[2], w3 = prow[3];
        const unsigned int w[NT] = {w0.x, w0.y, w0.z, w0.w,
                                    w1.x, w1.y, w1.z, w1.w,
                                    w2.x, w2.y, w2.z, w2.w,
                                    w3.x, w3.y, w3.z, w3.w};
        int dg = 0;
        int carr[NT];
        #pragma unroll
        for (int t = 0; t < NT; ++t) {
            const int hi = (int)(w[t] >> 16);
            carr[t] = (int)(w[t] & 0xFFFFu) - hi;
            dg += hi;
        }
        if (dg <= 0) continue;

        float x[D];
        #pragma unroll
        for (int j = 0; j < D; ++j) x[j] = reps[j * N + n];

        // wave-uniform R base: all lanes in the block share type ty
        const float* __restrict__ Rb = rmaps + (size_t)ty * NT * D * D;

        float y[D];
        #pragma unroll
        for (int r = 0; r < D; ++r) y[r] = 0.0f;

        #pragma unroll 1
        for (int t = 0; t < NT; ++t) {
            const float ct = (float)carr[t];
            const float* __restrict__ Rt = Rb + t * D * D;
            #pragma unroll
            for (int r = 0; r < D; ++r) {
                float s = 0.0f;
                #pragma unroll
                for (int j = 0; j < D; ++j)
                    s = fmaf(Rt[r * D + j], x[j], s);
                y[r] = fmaf(ct, s, y[r]);
            }
        }
        float ss = 0.0f;
        #pragma unroll
        for (int r = 0; r < D; ++r) ss = fmaf(y[r], y[r], ss);
        part += ss / (float)dg;
    }

    // block reduction -> single atomic
    #pragma unroll
    for (int off = 32; off > 0; off >>= 1)
        part += __shfl_down(part, off);
    __shared__ float wpart[4];
    const int lane = threadIdx.x & 63;
    const int wid  = threadIdx.x >> 6;
    if (lane == 0) wpart[wid] = part;
    __syncthreads();
    if (threadIdx.x == 0) {
        const float v = wpart[0] + wpart[1] + wpart[2] + wpart[3];
        if (v != 0.0f) atomicAdd(out, v);
    }
}

extern "C" void kernel_launch(void* const* d_in, const int* in_sizes, int n_in,
                              void* d_out, int out_size, void* d_ws, size_t ws_size,
                              hipStream_t stream) {
    const float* reps  = (const float*)d_in[0];   // [16, N]
    const float* rmaps = (const float*)d_in[1];   // [16,16,16,16]
    const int*   ei    = (const int*)d_in[2];     // [2, E]
    const int*   types = (const int*)d_in[3];     // [N]
    float* out = (float*)d_out;

    const int E = in_sizes[2] / 2;
    const int N = in_sizes[3];

    char* ws = (char*)d_ws;
    unsigned int* pk = (unsigned int*)(ws + OFF_PK);
    int* tcnt  = (int*)(ws + OFF_TCNT);
    int* tlist = (int*)(ws + OFF_TLIST);

    hipMemsetAsync(d_ws, 0, ZERO_BYTES, stream);
    hipMemsetAsync(d_out, 0, sizeof(float), stream);

    edge_kernel<<<(E / 4 + 255) / 256, 256, 0, stream>>>(ei, types, pk, E);
    list_kernel<<<(N + 255) / 256, 256, 0, stream>>>(types, tcnt, tlist, N);

    // grid-stride in x: (16,16) covers ~3125 nodes/type with safety via loop
    dim3 grid(16, NT);
    node_kernel<<<grid, 256, 0, stream>>>(reps, rmaps, pk, tcnt, tlist, out, N);
}